// Round 20
// baseline (25.085 us; speedup 1.0000x reference)
//
#include <hip/hip_runtime.h>
#include <hip/hip_bf16.h>
#include <cstdint>

// GraphLoss: layered lattice DAG (64 layers x 64 nodes, dense bipartite).
// result = sum(w*gold) + logsumexp over all source->sink paths of (-path weight).
//
// R20 = R19 (22.7us) with the fusion matmul optimized:
//  (1) cur-row LDS reads vectorized (f32x4 per row per 4-k block): 128 b128
//      reads/thread/matmul vs 256 b32 + 64 b128 -> DS-issue bound halved.
//      Accumulation order unchanged (k-ascending per accumulator) -> bitwise
//      identical product.
//  (2) next level's raw w prefetched into REGISTERS before the matmul
//      (compiler-visible loads; scheduler hoists them above the independent
//      fma loop; the post-matmul __syncthreads drains them) -> staging
//      latency hidden under the matmul.
// seq kernel = R19 verbatim (16 fused steps, depth-10 counted-vmcnt register
// pipeline, peeled 18/16/../0 tail, zero-in-flight exit, multiplicative
// renorm). Fusion->seq sync = stream launch order (never failed).
//
// Edge layout: e in [0,64): source->layer1 ; e = 64 + L*4096 + a*64 + b ;
// e = 258112 + j: layer64 node j -> sink.

typedef float v2f   __attribute__((ext_vector_type(2)));
typedef float f32x4 __attribute__((ext_vector_type(4)));
typedef unsigned int u32x4 __attribute__((ext_vector_type(4)));

#define NSTEP 16
#define SINK_BASE (64 + 63 * 4096)   // 258112
#define NGOLD 240
#define LDSTR 68                     // padded LDS row stride (f32 words)

// ---------------------------------------------------------------------------
// prep: 256 wgs x 256 thr. wgs 0..15: fused products P_g = prod M_(4g..4g+3)
// (g=15: 3 levels) + R8-layout bf16 pack. wgs 16..255: gold partials.
__global__ __launch_bounds__(256)
void prep_kernel(const int* __restrict__ g, const float* __restrict__ w,
                 unsigned int* __restrict__ wpk, float* __restrict__ partial, int E) {
    const int bid = blockIdx.x, t = threadIdx.x;

    if (bid < 16) {
        __shared__ __align__(16) float Xs[64 * LDSTR];
        __shared__ __align__(16) float Ys[64 * LDSTR];
        __shared__ __align__(16) float Zs[64 * LDSTR];
        const int gg = bid;
        const int L0 = 4 * gg;
        const int ng = (gg == 15) ? 3 : 4;

        const int rb = 4 * (t >> 4);     // 4 consecutive output rows
        const int c0 = 4 * (t & 15);     // 4 output cols

        // stage M_{L0} -> Xs and M_{L0+1} -> Ys (loads overlap, then exp)
        float r0[16], r1[16];
        {
            const float* s0 = w + 64 + L0 * 4096;
            const float* s1 = s0 + 4096;
            #pragma unroll
            for (int j = 0; j < 16; ++j) r0[j] = s0[j * 256 + t];
            #pragma unroll
            for (int j = 0; j < 16; ++j) r1[j] = s1[j * 256 + t];
            #pragma unroll
            for (int j = 0; j < 16; ++j) {
                const int idx = j * 256 + t;
                Xs[(idx >> 6) * LDSTR + (idx & 63)] = __expf(-r0[j]);
            }
            #pragma unroll
            for (int j = 0; j < 16; ++j) {
                const int idx = j * 256 + t;
                Ys[(idx >> 6) * LDSTR + (idx & 63)] = __expf(-r1[j]);
            }
        }
        __syncthreads();

        float* cur = Xs;
        float* oth = Zs;
        float rn[16];

        #pragma unroll 1
        for (int m = 1; m < ng; ++m) {
            // prefetch next level's raw w into regs (hidden under the matmul)
            if (m + 1 < ng) {
                const float* sn = w + 64 + (L0 + m + 1) * 4096;
                #pragma unroll
                for (int j = 0; j < 16; ++j) rn[j] = sn[j * 256 + t];
            }
            // oth = cur · Ys : per thread 4 rows x 4 cols, vector LDS reads
            f32x4 a0 = {0,0,0,0}, a1 = {0,0,0,0}, a2 = {0,0,0,0}, a3 = {0,0,0,0};
            #pragma unroll 4
            for (int kb = 0; kb < 16; ++kb) {
                const f32x4 x0 = *(const f32x4*)&cur[(rb + 0) * LDSTR + 4 * kb];
                const f32x4 x1 = *(const f32x4*)&cur[(rb + 1) * LDSTR + 4 * kb];
                const f32x4 x2 = *(const f32x4*)&cur[(rb + 2) * LDSTR + 4 * kb];
                const f32x4 x3 = *(const f32x4*)&cur[(rb + 3) * LDSTR + 4 * kb];
                #pragma unroll
                for (int dk = 0; dk < 4; ++dk) {
                    const f32x4 y = *(const f32x4*)&Ys[(4 * kb + dk) * LDSTR + c0];
                    const f32x4 s0 = {x0[dk], x0[dk], x0[dk], x0[dk]};
                    const f32x4 s1 = {x1[dk], x1[dk], x1[dk], x1[dk]};
                    const f32x4 s2 = {x2[dk], x2[dk], x2[dk], x2[dk]};
                    const f32x4 s3 = {x3[dk], x3[dk], x3[dk], x3[dk]};
                    a0 = __builtin_elementwise_fma(s0, y, a0);
                    a1 = __builtin_elementwise_fma(s1, y, a1);
                    a2 = __builtin_elementwise_fma(s2, y, a2);
                    a3 = __builtin_elementwise_fma(s3, y, a3);
                }
            }
            *(f32x4*)&oth[(rb + 0) * LDSTR + c0] = a0;
            *(f32x4*)&oth[(rb + 1) * LDSTR + c0] = a1;
            *(f32x4*)&oth[(rb + 2) * LDSTR + c0] = a2;
            *(f32x4*)&oth[(rb + 3) * LDSTR + c0] = a3;
            __syncthreads();             // all reads of Ys/cur done (+ prefetch drained)
            if (m + 1 < ng) {
                #pragma unroll
                for (int j = 0; j < 16; ++j) {
                    const int idx = j * 256 + t;
                    Ys[(idx >> 6) * LDSTR + (idx & 63)] = __expf(-rn[j]);
                }
            }
            { float* tmp = cur; cur = oth; oth = tmp; }
            __syncthreads();             // new cur + new Ys visible
        }

        // pack cur -> wpk block g (R8 layout, seq reads it verbatim)
        const int kc = (t & 63) >> 4;
        const int bb = 16 * (t >> 6) + (t & 15);
        #pragma unroll
        for (int h = 0; h < 2; ++h) {
            #pragma unroll
            for (int q = 0; q < 4; ++q) {
                const int k = 16 * kc + 2 * (4 * h + q);
                const float x0 = cur[k * LDSTR + bb];
                const float x1 = cur[(k + 1) * LDSTR + bb];
                uint32_t u0 = __float_as_uint(x0); u0 = (u0 + 0x7fffu + ((u0 >> 16) & 1u)) >> 16;
                uint32_t u1 = __float_as_uint(x1); u1 = (u1 + 0x7fffu + ((u1 >> 16) & 1u)) >> 16;
                wpk[gg * 2048 + h * 1024 + t * 4 + q] = u0 | (u1 << 16);
            }
        }
        return;
    }

    // -------- gold partial (240 wgs) --------
    const int gid = bid - 16;
    const bool is64 = (g[1] == 0);
    float s = 0.f;
    for (int e = gid * 256 + t; e < E; e += NGOLD * 256) {
        const int idx = 3 * e + 2;
        const int gv = is64 ? g[2 * idx] : g[idx];
        s += w[e] * (float)gv;
    }
    #pragma unroll
    for (int dd = 1; dd < 64; dd <<= 1) s += __shfl_xor(s, dd, 64);
    __shared__ float lsm[4];
    const int wv = t >> 6, ln = t & 63;
    if (ln == 0) lsm[wv] = s;
    __syncthreads();
    if (t == 0) partial[gid] = lsm[0] + lsm[1] + lsm[2] + lsm[3];
}

// ---------------------------------------------------------------------------
// seq: 256 threads / 4 waves (R19 verbatim), 16 fused steps.
__global__ __launch_bounds__(256, 1)
void seq_kernel(const float* __restrict__ w, const unsigned int* __restrict__ wpk,
                const float* __restrict__ partial, float* __restrict__ out) {
    __shared__ __align__(16) float ubuf[2][64];
    __shared__ float P[2];
    __shared__ float slds[64];

    const int tid = threadIdx.x;
    const int wv = tid >> 6, l = tid & 63;
    const int kc = l >> 4;
    const int bb = 16 * wv + (l & 15);

    const float z10 = -w[0];
    float LS = z10;
    float uf = __expf(-w[bb] - z10);       // u_1[bb]; u_1[0] = 1
    float wsink = w[SINK_BASE + bb];
    float gs = 0.f;
    #pragma unroll
    for (int i = 0; i < 3; ++i) gs += partial[l + (i << 6)];
    if (l < NGOLD - 192) gs += partial[l + 192];
    asm volatile("" : "+v"(LS), "+v"(uf), "+v"(wsink), "+v"(gs));

    if (l < 16) ubuf[0][bb] = uf;
    if (tid == 0) P[0] = 1.0f;

    const uint32_t voff  = (uint32_t)tid * 16u;
    const uint32_t voff2 = voff + 4096u;
    uintptr_t bcur = (uintptr_t)wpk;

    u32x4 q0a, q0b, q1a, q1b, q2a, q2b, q3a, q3b, q4a, q4b;
    u32x4 q5a, q5b, q6a, q6b, q7a, q7b, q8a, q8b, q9a, q9b;

#define LD1(DST, VO)                                                           \
    asm volatile("global_load_dwordx4 %0, %1, %2"                              \
                 : "=v"(DST) : "v"(VO), "s"(bcur))

#define ISSUE(QA, QB) do { LD1(QA, voff); LD1(QB, voff2); bcur += 8192u; } while (0)

#define BAR() do {                                                             \
    asm volatile("s_waitcnt lgkmcnt(0)" ::: "memory");                         \
    __builtin_amdgcn_s_barrier();                                              \
} while (0)

#define BODY(QA, QB, CB, WSTR, DOISS) {                                        \
    const float rho = P[CB];                                                   \
    const f32x4* uqp = (const f32x4*)ubuf[CB];                                 \
    f32x4 uu[4];                                                               \
    uu[0] = uqp[4 * kc + 0];                                                   \
    uu[1] = uqp[4 * kc + 1];                                                   \
    uu[2] = uqp[4 * kc + 2];                                                   \
    uu[3] = uqp[4 * kc + 3];                                                   \
    asm volatile("s_waitcnt vmcnt(" WSTR ")" ::: "memory");                    \
    __builtin_amdgcn_sched_barrier(0);                                         \
    asm volatile("" : "+v"(QA), "+v"(QB));                                     \
    float rc;                                                                  \
    asm("v_rcp_f32 %0, %1" : "=v"(rc) : "v"(rho));                             \
    v2f acc = {0.f, 0.f};                                                      \
    _Pragma("unroll")                                                          \
    for (int m = 0; m < 4; ++m) {                                              \
        _Pragma("unroll")                                                      \
        for (int pp = 0; pp < 2; ++pp) {                                       \
            const int j2 = 2 * m + pp;                                         \
            const unsigned int wd = (j2 < 4) ? QA[j2] : QB[j2 - 4];            \
            v2f wp, up;                                                        \
            wp[0] = __uint_as_float(wd << 16);                                 \
            wp[1] = __uint_as_float(wd & 0xffff0000u);                         \
            up[0] = uu[m][2 * pp]; up[1] = uu[m][2 * pp + 1];                  \
            acc = __builtin_elementwise_fma(wp, up, acc);                      \
        }                                                                      \
    }                                                                          \
    float p = acc[0] + acc[1];                                                 \
    p += __shfl_xor(p, 16, 64);                                                \
    p += __shfl_xor(p, 32, 64);           /* p = y[bb] in all lanes */         \
    uf = p * rc;                                                               \
    if (l < 16) ubuf[(CB) ^ 1][bb] = uf;                                       \
    if (tid == 0) P[(CB) ^ 1] = uf;                                            \
    LS += __logf(rho);                    /* off critical path */              \
    if (DOISS) ISSUE(QA, QB);                                                  \
    BAR();                                                                     \
}

    // prologue: steps 0..9 in flight (20 loads)
    ISSUE(q0a, q0b); ISSUE(q1a, q1b); ISSUE(q2a, q2b); ISSUE(q3a, q3b);
    ISSUE(q4a, q4b); ISSUE(q5a, q5b); ISSUE(q6a, q6b); ISSUE(q7a, q7b);
    ISSUE(q8a, q8b); ISSUE(q9a, q9b);
    BAR();             // ubuf[0]/P[0] visible

    // 16 bodies; issues end at body 5 (step 15); exact peeled waits leave
    // ZERO loads in flight after body 15.
    BODY(q0a, q0b, 0, "18", 1)   // 0  -> issues S10
    BODY(q1a, q1b, 1, "18", 1)   // 1  -> S11
    BODY(q2a, q2b, 0, "18", 1)   // 2  -> S12
    BODY(q3a, q3b, 1, "18", 1)   // 3  -> S13
    BODY(q4a, q4b, 0, "18", 1)   // 4  -> S14
    BODY(q5a, q5b, 1, "18", 1)   // 5  -> S15 (last issue)
    BODY(q6a, q6b, 0, "18", 0)   // 6
    BODY(q7a, q7b, 1, "16", 0)   // 7
    BODY(q8a, q8b, 0, "14", 0)   // 8
    BODY(q9a, q9b, 1, "12", 0)   // 9
    BODY(q0a, q0b, 0, "10", 0)   // 10
    BODY(q1a, q1b, 1, "8",  0)   // 11
    BODY(q2a, q2b, 0, "6",  0)   // 12
    BODY(q3a, q3b, 1, "4",  0)   // 13
    BODY(q4a, q4b, 0, "2",  0)   // 14
    BODY(q5a, q5b, 1, "0",  0)   // 15

    // sink fold staging: m[bb] = LS + log(uf) - wsink
    const float m0 = LS + __logf(uf) - wsink;
    if (l < 16) slds[bb] = m0;
    BAR();

    if (wv == 0) {
        float m = slds[l];
        float s = 1.0f;
        #pragma unroll
        for (int d = 1; d < 64; d <<= 1) {
            const float om = __shfl_xor(m, d, 64);
            const float os = __shfl_xor(s, d, 64);
            const float nm = fmaxf(m, om);
            s = __expf(m - nm) * s + __expf(om - nm) * os;
            m = nm;
        }
        const float vsink = m + __logf(s);
        #pragma unroll
        for (int d = 1; d < 64; d <<= 1) gs += __shfl_xor(gs, d, 64);
        if (l == 0) out[0] = gs + vsink;
    }
}

extern "C" void kernel_launch(void* const* d_in, const int* in_sizes, int n_in,
                              void* d_out, int out_size, void* d_ws, size_t ws_size,
                              hipStream_t stream) {
    const int*   g = (const int*)d_in[0];
    const float* w = (const float*)d_in[1];
    float* out     = (float*)d_out;
    unsigned int* wpk = (unsigned int*)d_ws;        // 16*2048 u32
    float* partial = (float*)(wpk + 16 * 2048);     // 240 floats
    const int E = in_sizes[0] / 3;                  // 258176

    prep_kernel<<<256, 256, 0, stream>>>(g, w, wpk, partial, E);
    seq_kernel<<<1, 256, 0, stream>>>(w, wpk, partial, out);
}

// Round 21
// 21.673 us; speedup vs baseline: 1.1574x; 1.1574x over previous
//
#include <hip/hip_runtime.h>
#include <hip/hip_bf16.h>
#include <cstdint>

// GraphLoss: layered lattice DAG (64 layers x 64 nodes, dense bipartite).
// result = sum(w*gold) + logsumexp over all source->sink paths of (-path weight).
//
// R21 = R19 (22.7us, champion) + ONE isolated change in the fusion matmul:
// x-reads k-vectorized (1 b128 per row per 4-k block instead of 4 scalar
// b32) -> per-thread DS instructions per matmul 320 -> 128. FMA order per
// accumulator stays k-ascending (bitwise-identical product). No register
// prefetch (R20's second change - suspected VGPR-pressure regression), no
// staging restructure: everything else is R19 verbatim.
//
// seq = R19 verbatim: 16 fused steps, depth-10 counted-vmcnt register
// pipeline (peeled 18/16/../0 tail, zero-in-flight exit, "+v" pin after
// wait, sched_barrier fences, raw s_barrier + lgkmcnt(0) cadence),
// multiplicative renorm u=p*rcp(rho), LS+=log(rho) off-path.
//
// Edge layout: e in [0,64): source->layer1 ; e = 64 + L*4096 + a*64 + b ;
// e = 258112 + j: layer64 node j -> sink.

typedef float v2f   __attribute__((ext_vector_type(2)));
typedef float f32x4 __attribute__((ext_vector_type(4)));
typedef unsigned int u32x4 __attribute__((ext_vector_type(4)));

#define NSTEP 16
#define SINK_BASE (64 + 63 * 4096)   // 258112
#define NGOLD 240
#define LDSTR 68                     // padded LDS row stride (f32 words); 272B rows keep 16B alignment

// ---------------------------------------------------------------------------
// prep: 256 wgs x 256 thr. wgs 0..15: fused products P_g = prod M_(4g..4g+3)
// (g=15: 3 levels) + R8-layout bf16 pack. wgs 16..255: gold partials.
__global__ __launch_bounds__(256)
void prep_kernel(const int* __restrict__ g, const float* __restrict__ w,
                 unsigned int* __restrict__ wpk, float* __restrict__ partial, int E) {
    const int bid = blockIdx.x, t = threadIdx.x;

    if (bid < 16) {
        __shared__ __align__(16) float Xs[64 * LDSTR];
        __shared__ __align__(16) float Ys[64 * LDSTR];
        __shared__ __align__(16) float Zs[64 * LDSTR];
        const int gg = bid;
        const int L0 = 4 * gg;
        const int ng = (gg == 15) ? 3 : 4;

        // load+exp M_{L0} -> Xs (R19 verbatim)
        {
            const float* src = w + 64 + L0 * 4096;
            #pragma unroll
            for (int j = 0; j < 16; ++j) {
                const int idx = j * 256 + t;
                Xs[(idx >> 6) * LDSTR + (idx & 63)] = __expf(-src[idx]);
            }
        }
        float* cur = Xs;
        float* oth = Zs;
        const int rb = 4 * (t >> 4);     // 4 consecutive output rows
        const int c0 = 4 * (t & 15);     // 4 output cols

        #pragma unroll 1
        for (int m = 1; m < ng; ++m) {
            const float* src = w + 64 + (L0 + m) * 4096;
            #pragma unroll
            for (int j = 0; j < 16; ++j) {
                const int idx = j * 256 + t;
                Ys[(idx >> 6) * LDSTR + (idx & 63)] = __expf(-src[idx]);
            }
            __syncthreads();             // X/prev product + Y ready
            // oth = cur · Ys  (4 rows x 4 cols per thread; x k-vectorized)
            f32x4 a0 = {0,0,0,0}, a1 = {0,0,0,0}, a2 = {0,0,0,0}, a3 = {0,0,0,0};
            #pragma unroll 2
            for (int kb = 0; kb < 16; ++kb) {
                const f32x4 x0 = *(const f32x4*)&cur[(rb + 0) * LDSTR + 4 * kb];
                const f32x4 x1 = *(const f32x4*)&cur[(rb + 1) * LDSTR + 4 * kb];
                const f32x4 x2 = *(const f32x4*)&cur[(rb + 2) * LDSTR + 4 * kb];
                const f32x4 x3 = *(const f32x4*)&cur[(rb + 3) * LDSTR + 4 * kb];
                #pragma unroll
                for (int dk = 0; dk < 4; ++dk) {
                    const f32x4 y = *(const f32x4*)&Ys[(4 * kb + dk) * LDSTR + c0];
                    const f32x4 s0 = {x0[dk], x0[dk], x0[dk], x0[dk]};
                    const f32x4 s1 = {x1[dk], x1[dk], x1[dk], x1[dk]};
                    const f32x4 s2 = {x2[dk], x2[dk], x2[dk], x2[dk]};
                    const f32x4 s3 = {x3[dk], x3[dk], x3[dk], x3[dk]};
                    a0 = __builtin_elementwise_fma(s0, y, a0);
                    a1 = __builtin_elementwise_fma(s1, y, a1);
                    a2 = __builtin_elementwise_fma(s2, y, a2);
                    a3 = __builtin_elementwise_fma(s3, y, a3);
                }
            }
            *(f32x4*)&oth[(rb + 0) * LDSTR + c0] = a0;
            *(f32x4*)&oth[(rb + 1) * LDSTR + c0] = a1;
            *(f32x4*)&oth[(rb + 2) * LDSTR + c0] = a2;
            *(f32x4*)&oth[(rb + 3) * LDSTR + c0] = a3;
            __syncthreads();             // product done before Y reuse
            float* tmp = cur; cur = oth; oth = tmp;
        }

        // pack cur -> wpk block g (R8 layout, seq reads it verbatim)
        const int kc = (t & 63) >> 4;
        const int bb = 16 * (t >> 6) + (t & 15);
        #pragma unroll
        for (int h = 0; h < 2; ++h) {
            #pragma unroll
            for (int q = 0; q < 4; ++q) {
                const int k = 16 * kc + 2 * (4 * h + q);
                const float x0 = cur[k * LDSTR + bb];
                const float x1 = cur[(k + 1) * LDSTR + bb];
                uint32_t u0 = __float_as_uint(x0); u0 = (u0 + 0x7fffu + ((u0 >> 16) & 1u)) >> 16;
                uint32_t u1 = __float_as_uint(x1); u1 = (u1 + 0x7fffu + ((u1 >> 16) & 1u)) >> 16;
                wpk[gg * 2048 + h * 1024 + t * 4 + q] = u0 | (u1 << 16);
            }
        }
        return;
    }

    // -------- gold partial (240 wgs) --------
    const int gid = bid - 16;
    const bool is64 = (g[1] == 0);
    float s = 0.f;
    for (int e = gid * 256 + t; e < E; e += NGOLD * 256) {
        const int idx = 3 * e + 2;
        const int gv = is64 ? g[2 * idx] : g[idx];
        s += w[e] * (float)gv;
    }
    #pragma unroll
    for (int dd = 1; dd < 64; dd <<= 1) s += __shfl_xor(s, dd, 64);
    __shared__ float lsm[4];
    const int wv = t >> 6, ln = t & 63;
    if (ln == 0) lsm[wv] = s;
    __syncthreads();
    if (t == 0) partial[gid] = lsm[0] + lsm[1] + lsm[2] + lsm[3];
}

// ---------------------------------------------------------------------------
// seq: 256 threads / 4 waves (R19 verbatim), 16 fused steps.
__global__ __launch_bounds__(256, 1)
void seq_kernel(const float* __restrict__ w, const unsigned int* __restrict__ wpk,
                const float* __restrict__ partial, float* __restrict__ out) {
    __shared__ __align__(16) float ubuf[2][64];
    __shared__ float P[2];
    __shared__ float slds[64];

    const int tid = threadIdx.x;
    const int wv = tid >> 6, l = tid & 63;
    const int kc = l >> 4;
    const int bb = 16 * wv + (l & 15);

    const float z10 = -w[0];
    float LS = z10;
    float uf = __expf(-w[bb] - z10);       // u_1[bb]; u_1[0] = 1
    float wsink = w[SINK_BASE + bb];
    float gs = 0.f;
    #pragma unroll
    for (int i = 0; i < 3; ++i) gs += partial[l + (i << 6)];
    if (l < NGOLD - 192) gs += partial[l + 192];
    asm volatile("" : "+v"(LS), "+v"(uf), "+v"(wsink), "+v"(gs));

    if (l < 16) ubuf[0][bb] = uf;
    if (tid == 0) P[0] = 1.0f;

    const uint32_t voff  = (uint32_t)tid * 16u;
    const uint32_t voff2 = voff + 4096u;
    uintptr_t bcur = (uintptr_t)wpk;

    u32x4 q0a, q0b, q1a, q1b, q2a, q2b, q3a, q3b, q4a, q4b;
    u32x4 q5a, q5b, q6a, q6b, q7a, q7b, q8a, q8b, q9a, q9b;

#define LD1(DST, VO)                                                           \
    asm volatile("global_load_dwordx4 %0, %1, %2"                              \
                 : "=v"(DST) : "v"(VO), "s"(bcur))

#define ISSUE(QA, QB) do { LD1(QA, voff); LD1(QB, voff2); bcur += 8192u; } while (0)

#define BAR() do {                                                             \
    asm volatile("s_waitcnt lgkmcnt(0)" ::: "memory");                         \
    __builtin_amdgcn_s_barrier();                                              \
} while (0)

#define BODY(QA, QB, CB, WSTR, DOISS) {                                        \
    const float rho = P[CB];                                                   \
    const f32x4* uqp = (const f32x4*)ubuf[CB];                                 \
    f32x4 uu[4];                                                               \
    uu[0] = uqp[4 * kc + 0];                                                   \
    uu[1] = uqp[4 * kc + 1];                                                   \
    uu[2] = uqp[4 * kc + 2];                                                   \
    uu[3] = uqp[4 * kc + 3];                                                   \
    asm volatile("s_waitcnt vmcnt(" WSTR ")" ::: "memory");                    \
    __builtin_amdgcn_sched_barrier(0);                                         \
    asm volatile("" : "+v"(QA), "+v"(QB));                                     \
    float rc;                                                                  \
    asm("v_rcp_f32 %0, %1" : "=v"(rc) : "v"(rho));                             \
    v2f acc = {0.f, 0.f};                                                      \
    _Pragma("unroll")                                                          \
    for (int m = 0; m < 4; ++m) {                                              \
        _Pragma("unroll")                                                      \
        for (int pp = 0; pp < 2; ++pp) {                                       \
            const int j2 = 2 * m + pp;                                         \
            const unsigned int wd = (j2 < 4) ? QA[j2] : QB[j2 - 4];            \
            v2f wp, up;                                                        \
            wp[0] = __uint_as_float(wd << 16);                                 \
            wp[1] = __uint_as_float(wd & 0xffff0000u);                         \
            up[0] = uu[m][2 * pp]; up[1] = uu[m][2 * pp + 1];                  \
            acc = __builtin_elementwise_fma(wp, up, acc);                      \
        }                                                                      \
    }                                                                          \
    float p = acc[0] + acc[1];                                                 \
    p += __shfl_xor(p, 16, 64);                                                \
    p += __shfl_xor(p, 32, 64);           /* p = y[bb] in all lanes */         \
    uf = p * rc;                                                               \
    if (l < 16) ubuf[(CB) ^ 1][bb] = uf;                                       \
    if (tid == 0) P[(CB) ^ 1] = uf;                                            \
    LS += __logf(rho);                    /* off critical path */              \
    if (DOISS) ISSUE(QA, QB);                                                  \
    BAR();                                                                     \
}

    // prologue: steps 0..9 in flight (20 loads)
    ISSUE(q0a, q0b); ISSUE(q1a, q1b); ISSUE(q2a, q2b); ISSUE(q3a, q3b);
    ISSUE(q4a, q4b); ISSUE(q5a, q5b); ISSUE(q6a, q6b); ISSUE(q7a, q7b);
    ISSUE(q8a, q8b); ISSUE(q9a, q9b);
    BAR();             // ubuf[0]/P[0] visible

    // 16 bodies; issues end at body 5 (step 15); exact peeled waits leave
    // ZERO loads in flight after body 15.
    BODY(q0a, q0b, 0, "18", 1)   // 0  -> issues S10
    BODY(q1a, q1b, 1, "18", 1)   // 1  -> S11
    BODY(q2a, q2b, 0, "18", 1)   // 2  -> S12
    BODY(q3a, q3b, 1, "18", 1)   // 3  -> S13
    BODY(q4a, q4b, 0, "18", 1)   // 4  -> S14
    BODY(q5a, q5b, 1, "18", 1)   // 5  -> S15 (last issue)
    BODY(q6a, q6b, 0, "18", 0)   // 6
    BODY(q7a, q7b, 1, "16", 0)   // 7
    BODY(q8a, q8b, 0, "14", 0)   // 8
    BODY(q9a, q9b, 1, "12", 0)   // 9
    BODY(q0a, q0b, 0, "10", 0)   // 10
    BODY(q1a, q1b, 1, "8",  0)   // 11
    BODY(q2a, q2b, 0, "6",  0)   // 12
    BODY(q3a, q3b, 1, "4",  0)   // 13
    BODY(q4a, q4b, 0, "2",  0)   // 14
    BODY(q5a, q5b, 1, "0",  0)   // 15

    // sink fold staging: m[bb] = LS + log(uf) - wsink
    const float m0 = LS + __logf(uf) - wsink;
    if (l < 16) slds[bb] = m0;
    BAR();

    if (wv == 0) {
        float m = slds[l];
        float s = 1.0f;
        #pragma unroll
        for (int d = 1; d < 64; d <<= 1) {
            const float om = __shfl_xor(m, d, 64);
            const float os = __shfl_xor(s, d, 64);
            const float nm = fmaxf(m, om);
            s = __expf(m - nm) * s + __expf(om - nm) * os;
            m = nm;
        }
        const float vsink = m + __logf(s);
        #pragma unroll
        for (int d = 1; d < 64; d <<= 1) gs += __shfl_xor(gs, d, 64);
        if (l == 0) out[0] = gs + vsink;
    }
}

extern "C" void kernel_launch(void* const* d_in, const int* in_sizes, int n_in,
                              void* d_out, int out_size, void* d_ws, size_t ws_size,
                              hipStream_t stream) {
    const int*   g = (const int*)d_in[0];
    const float* w = (const float*)d_in[1];
    float* out     = (float*)d_out;
    unsigned int* wpk = (unsigned int*)d_ws;        // 16*2048 u32
    float* partial = (float*)(wpk + 16 * 2048);     // 240 floats
    const int E = in_sizes[0] / 3;                  // 258176

    prep_kernel<<<256, 256, 0, stream>>>(g, w, wpk, partial, E);
    seq_kernel<<<1, 256, 0, stream>>>(w, wpk, partial, out);
}